// Round 4
// baseline (578.589 us; speedup 1.0000x reference)
//
#include <hip/hip_runtime.h>

#define BN 8192
#define GIN 768

// ---- ws layout (bytes), total ~18.5 MB ----
#define O_ROUTE_I 0UL                                   // int[BN][2]
#define O_ROUTE_W (O_ROUTE_I + (size_t)BN*2*4)          // float[BN][2]
#define O_COUNTS  (O_ROUTE_W + (size_t)BN*2*4)          // int[8] (padded to 256B)
#define O_LISTS   (O_COUNTS + 256)                      // int[8][BN]
#define O_PW2T    (O_LISTS + (size_t)8*BN*4)            // float[8][64][128]
#define O_PW3T    (O_PW2T + (size_t)8*64*128*4)         // float[8][128][256]
#define O_SLOT    (O_PW3T + (size_t)8*128*256*4)        // float[2*BN][256]

// ---------------- K0: weight transpose + zero counters ----------------
__global__ __launch_bounds__(256) void k0_prep(const float* __restrict__ pw2w,
                                               const float* __restrict__ pw3w,
                                               float* __restrict__ pw2t,
                                               float* __restrict__ pw3t,
                                               int* __restrict__ counts)
{
    int tid = blockIdx.x * 256 + threadIdx.x;
    if (tid < 8) counts[tid] = 0;
    // pw2_w: [8][128][64] -> pw2t: [8][64][128]
    for (int idx = tid; idx < 8 * 128 * 64; idx += 256 * 256) {
        int e = idx >> 13; int r = idx & 8191; int oc = r >> 6; int c = r & 63;
        pw2t[(size_t)e * 8192 + c * 128 + oc] = pw2w[idx];
    }
    // pw3_w: [8][256][128] -> pw3t: [8][128][256]
    for (int idx = tid; idx < 8 * 256 * 128; idx += 256 * 256) {
        int e = idx >> 15; int r = idx & 32767; int oc = r >> 7; int c = r & 127;
        pw3t[(size_t)e * 32768 + c * 256 + oc] = pw3w[idx];
    }
}

// ---------------- K1: gate GEMM + top2 + list build ----------------
// grid 256 blocks x 256 thr; tile = 32 patches x 128 hidden, Kc=32
__global__ __launch_bounds__(256) void k1_gate(
    const float* __restrict__ x, const float* __restrict__ w1,
    const float* __restrict__ b1, const float* __restrict__ w2,
    const float* __restrict__ b2,
    int* __restrict__ route_i, float* __restrict__ route_w,
    int* __restrict__ counts, int* __restrict__ lists)
{
    __shared__ __align__(16) float A[32][44];    // [k][p]
    __shared__ __align__(16) float Wl[32][132];  // [k][h]
    __shared__ float hl[32][132];
    __shared__ float ll[32][8];

    int tid = threadIdx.x;
    int pblk = blockIdx.x * 32;

    int pgrp = tid & 7;        // p0 = pgrp*4
    int hgrp = tid >> 3;       // h0 = hgrp*4 (0..127)
    float acc[4][4] = {};

    // staging roles
    int sp  = tid >> 3;        // patch-local 0..31 (A staging)
    int sk4 = (tid & 7) * 4;   // k offset 0..28
    int swh = tid >> 1;        // h 0..127 (W staging)
    int swk = (tid & 1) * 16;  // k offset 0 / 16

    int patchA = pblk + sp;
    int bA = patchA >> 8; int nA = patchA & 255; int hpA = nA >> 4; int wpA = nA & 15;

    for (int kc = 0; kc < GIN; kc += 32) {
        // stage A (32p x 32k), transposed to [k][p]
        {
            int k = kc + sk4;
            int c = k >> 8; int rem = k & 255; int ri = rem >> 4; int j = rem & 15;
            const float* src = x + (((size_t)(bA * 3 + c) * 256 + hpA * 16 + ri) * 256 + wpA * 16 + j);
            float4 a4 = *reinterpret_cast<const float4*>(src);
            A[sk4 + 0][sp] = a4.x; A[sk4 + 1][sp] = a4.y;
            A[sk4 + 2][sp] = a4.z; A[sk4 + 3][sp] = a4.w;
        }
        // stage W (128h x 32k), transposed to [k][h]
        {
            const float* wsrc = w1 + (size_t)swh * GIN + kc + swk;
            #pragma unroll
            for (int q = 0; q < 4; q++) {
                float4 w4 = *reinterpret_cast<const float4*>(wsrc + q * 4);
                Wl[swk + q * 4 + 0][swh] = w4.x; Wl[swk + q * 4 + 1][swh] = w4.y;
                Wl[swk + q * 4 + 2][swh] = w4.z; Wl[swk + q * 4 + 3][swh] = w4.w;
            }
        }
        __syncthreads();
        float cacc[4][4] = {};   // per-chunk partial (reduces rounding error)
        #pragma unroll
        for (int k2 = 0; k2 < 32; k2++) {
            float4 av = *reinterpret_cast<const float4*>(&A[k2][pgrp * 4]);
            float4 wv = *reinterpret_cast<const float4*>(&Wl[k2][hgrp * 4]);
            float aa[4] = {av.x, av.y, av.z, av.w};
            float ww[4] = {wv.x, wv.y, wv.z, wv.w};
            #pragma unroll
            for (int i = 0; i < 4; i++) {
                #pragma unroll
                for (int jj = 0; jj < 4; jj++) cacc[i][jj] += aa[i] * ww[jj];
            }
        }
        #pragma unroll
        for (int i = 0; i < 4; i++) {
            #pragma unroll
            for (int jj = 0; jj < 4; jj++) acc[i][jj] += cacc[i][jj];
        }
        __syncthreads();
    }

    // h = relu(acc + b1) -> hl
    #pragma unroll
    for (int jj = 0; jj < 4; jj++) {
        float bb = b1[hgrp * 4 + jj];
        #pragma unroll
        for (int i = 0; i < 4; i++) {
            float v = acc[i][jj] + bb;
            hl[pgrp * 4 + i][hgrp * 4 + jj] = v > 0.f ? v : 0.f;
        }
    }
    __syncthreads();

    // logits: 32p x 8e
    {
        int lp = tid >> 3; int le = tid & 7;
        float lacc = b2[le];
        const float* wrow = w2 + le * 128;
        for (int h = 0; h < 128; h++) lacc += hl[lp][h] * wrow[h];
        ll[lp][le] = lacc;
    }
    __syncthreads();

    if (tid < 32) {
        int patch = pblk + tid;
        float v[8];
        #pragma unroll
        for (int e = 0; e < 8; e++) v[e] = ll[tid][e];
        // top-2, ties -> lower index (matches lax.top_k)
        int e0 = 0; float m0 = v[0];
        #pragma unroll
        for (int e = 1; e < 8; e++) if (v[e] > m0) { m0 = v[e]; e0 = e; }
        int e1 = -1; float m1 = -3.0e38f;
        #pragma unroll
        for (int e = 0; e < 8; e++) if (e != e0 && v[e] > m1) { m1 = v[e]; e1 = e; }
        float t = expf(m1 - m0);       // m0 is the max
        float w0 = 1.f / (1.f + t);
        float w1v = t * w0;
        route_i[patch * 2] = e0; route_i[patch * 2 + 1] = e1;
        route_w[patch * 2] = w0; route_w[patch * 2 + 1] = w1v;
        int p0 = atomicAdd(&counts[e0], 1);
        lists[e0 * BN + p0] = patch * 2;
        int p1 = atomicAdd(&counts[e1], 1);
        lists[e1 * BN + p1] = patch * 2 + 1;
    }
}

// ---------------- K23: full expert pipeline, expert-binned, 4 entries/block ----------
// BARRIER-FREE: each wave owns one entry end-to-end; all LDS traffic is
// wave-private (DS ops from one wave execute in order; compiler preserves
// may-alias load/store order). LDS = 4 x 2560 floats = 40960 B -> 4 blocks/CU.
// Per-entry slice (floats), time-multiplexed:
//   pl  @0     [3][16][20] =  960   (phase A write, B read)
//   d1  @2048  [3][64]     =  192   (phase B write, C read)
//   d2t @0     [16][68]    = 1088   (phase C write, D read)  aliases dead pl
//   p2  @0     [128][16]sw = 2048   (phase D write, E read)  aliases d2t: all
//                                    D-reads precede D-writes in program order
//   d3  @2048  [128][4]    =  512   (phase E write, F read)  aliases dead d1
// p2 swizzle: addr = ch*16 + ((pos + (ch>>3)) & 15)  (write conflicts 16->4-way)
__global__ __launch_bounds__(256, 4) void k23_expert(
    const float* __restrict__ x, const int* __restrict__ counts,
    const int* __restrict__ lists,
    const float* __restrict__ dw1w, const float* __restrict__ dw1b,
    const float* __restrict__ pw1w, const float* __restrict__ pw1b,
    const float* __restrict__ dw2w, const float* __restrict__ dw2b,
    const float* __restrict__ pw2t, const float* __restrict__ pw2b,
    const float* __restrict__ dw3w, const float* __restrict__ dw3b,
    const float* __restrict__ pw3t, const float* __restrict__ pw3b,
    float* __restrict__ slot)
{
    __shared__ __align__(16) float buf[4][2560];

    int e = blockIdx.x & 7;
    int chunk = blockIdx.x >> 3;
    int cnt = counts[e];
    int base = chunk * 4;
    if (base >= cnt) return;
    int tid = threadIdx.x;
    int en = tid >> 6; int l = tid & 63;       // one wave per entry
    if (base + en >= cnt) return;              // wave-uniform exit
    int pslot = lists[e * BN + base + en];     // wave-uniform scalar load
    int patch = pslot >> 1;
    int b = patch >> 8, nn = patch & 255, hp = nn >> 4, wp = nn & 15;

    float* pl  = buf[en];
    float* d1  = buf[en] + 2048;
    float* d2t = buf[en];
    float* p2  = buf[en];
    float* d3  = buf[en] + 2048;

    // ---- phase A: stage patch [3][16][20] ----
    {
        int r = l >> 2; int j4 = (l & 3) * 4;
        #pragma unroll
        for (int c = 0; c < 3; c++) {
            const float* src = x + (((size_t)(b * 3 + c) * 256 + hp * 16 + r) * 256 + wp * 16 + j4);
            float4 v = *reinterpret_cast<const float4*>(src);
            *reinterpret_cast<float4*>(&pl[c * 320 + r * 20 + j4]) = v;
        }
    }

    // ---- phase B: dw1 3ch x 8x8 ----
    {
        int oh = l >> 3, ow = l & 7;
        #pragma unroll
        for (int c = 0; c < 3; c++) {
            const float* w9 = dw1w + (e * 3 + c) * 9;
            float acc = dw1b[e * 3 + c];
            #pragma unroll
            for (int ki = 0; ki < 3; ki++) {
                int ih = oh * 2 - 1 + ki;
                if ((unsigned)ih < 16u) {
                    #pragma unroll
                    for (int kj = 0; kj < 3; kj++) {
                        int iw = ow * 2 - 1 + kj;
                        if ((unsigned)iw < 16u) acc += pl[c * 320 + ih * 20 + iw] * w9[ki * 3 + kj];
                    }
                }
            }
            d1[c * 64 + l] = acc > 0.f ? acc : 0.f;
        }
    }

    // ---- phase C: pw1 (64oc, K=3) fused with dw2 per channel ----
    {
        const float* w3 = pw1w + (e * 64 + l) * 3;
        float pw0 = w3[0], pw1v = w3[1], pw2v = w3[2];
        float pb = pw1b[e * 64 + l];
        float p1r[64];
        #pragma unroll
        for (int p4 = 0; p4 < 16; p4++) {
            float4 a0 = *reinterpret_cast<const float4*>(&d1[0 * 64 + p4 * 4]);
            float4 a1 = *reinterpret_cast<const float4*>(&d1[1 * 64 + p4 * 4]);
            float4 a2 = *reinterpret_cast<const float4*>(&d1[2 * 64 + p4 * 4]);
            float v0 = pb + a0.x * pw0 + a1.x * pw1v + a2.x * pw2v;
            float v1 = pb + a0.y * pw0 + a1.y * pw1v + a2.y * pw2v;
            float v2 = pb + a0.z * pw0 + a1.z * pw1v + a2.z * pw2v;
            float v3 = pb + a0.w * pw0 + a1.w * pw1v + a2.w * pw2v;
            p1r[p4 * 4 + 0] = v0 > 0.f ? v0 : 0.f;
            p1r[p4 * 4 + 1] = v1 > 0.f ? v1 : 0.f;
            p1r[p4 * 4 + 2] = v2 > 0.f ? v2 : 0.f;
            p1r[p4 * 4 + 3] = v3 > 0.f ? v3 : 0.f;
        }
        const float* w9 = dw2w + (e * 64 + l) * 9;
        float wd[9];
        #pragma unroll
        for (int i = 0; i < 9; i++) wd[i] = w9[i];
        float bd = dw2b[e * 64 + l];
        #pragma unroll
        for (int pos = 0; pos < 16; pos++) {
            int oh = pos >> 2, ow = pos & 3;
            float acc = bd;
            #pragma unroll
            for (int ki = 0; ki < 3; ki++) {
                int ih = oh * 2 - 1 + ki;
                if ((unsigned)ih < 8u) {
                    #pragma unroll
                    for (int kj = 0; kj < 3; kj++) {
                        int iw = ow * 2 - 1 + kj;
                        if ((unsigned)iw < 8u) acc += p1r[ih * 8 + iw] * wd[ki * 3 + kj];
                    }
                }
            }
            d2t[pos * 68 + l] = acc > 0.f ? acc : 0.f;   // [pos][ch]
        }
    }

    // ---- phase D: pw2 128oc x 16pos, K=64 (reads d2t, then writes p2) ----
    {
        int ocg = l & 15; int pq = l >> 4;
        int oc0 = ocg * 8; int p0 = pq * 4;
        float acc[8][4] = {};
        const float* wbase = pw2t + (size_t)e * 8192;   // [c][128]
        for (int c4 = 0; c4 < 16; c4++) {
            float4 a0 = *reinterpret_cast<const float4*>(&d2t[(p0 + 0) * 68 + c4 * 4]);
            float4 a1 = *reinterpret_cast<const float4*>(&d2t[(p0 + 1) * 68 + c4 * 4]);
            float4 a2 = *reinterpret_cast<const float4*>(&d2t[(p0 + 2) * 68 + c4 * 4]);
            float4 a3 = *reinterpret_cast<const float4*>(&d2t[(p0 + 3) * 68 + c4 * 4]);
            float av[4][4] = {{a0.x, a1.x, a2.x, a3.x}, {a0.y, a1.y, a2.y, a3.y},
                              {a0.z, a1.z, a2.z, a3.z}, {a0.w, a1.w, a2.w, a3.w}};
            #pragma unroll
            for (int cc = 0; cc < 4; cc++) {
                int c = c4 * 4 + cc;
                float4 wa = *reinterpret_cast<const float4*>(wbase + c * 128 + oc0);
                float4 wb = *reinterpret_cast<const float4*>(wbase + c * 128 + oc0 + 4);
                float wv[8] = {wa.x, wa.y, wa.z, wa.w, wb.x, wb.y, wb.z, wb.w};
                #pragma unroll
                for (int j = 0; j < 8; j++) {
                    #pragma unroll
                    for (int i = 0; i < 4; i++) acc[j][i] += wv[j] * av[cc][i];
                }
            }
        }
        #pragma unroll
        for (int j = 0; j < 8; j++) {
            float bb = pw2b[e * 128 + oc0 + j];
            #pragma unroll
            for (int i = 0; i < 4; i++) {
                float v = acc[j][i] + bb;
                // swizzled store: ch = oc0+j, pos = p0+i, ch>>3 == ocg
                p2[(oc0 + j) * 16 + ((p0 + i + ocg) & 15)] = v > 0.f ? v : 0.f;
            }
        }
    }

    // ---- phase E: dw3 128ch x 2x2 (reads swizzled p2) ----
    {
        #pragma unroll
        for (int chb = 0; chb < 128; chb += 64) {
            int ch = chb + l;
            int grp = ch >> 3;
            const float* w9 = dw3w + (e * 128 + ch) * 9;
            float bb = dw3b[e * 128 + ch];
            #pragma unroll
            for (int pos = 0; pos < 4; pos++) {
                int oh = pos >> 1, ow = pos & 1;
                float acc = bb;
                #pragma unroll
                for (int ki = 0; ki < 3; ki++) {
                    int ih = oh * 2 - 1 + ki;
                    if ((unsigned)ih < 4u) {
                        #pragma unroll
                        for (int kj = 0; kj < 3; kj++) {
                            int iw = ow * 2 - 1 + kj;
                            if ((unsigned)iw < 4u)
                                acc += p2[ch * 16 + ((ih * 4 + iw + grp) & 15)] * w9[ki * 3 + kj];
                        }
                    }
                }
                d3[ch * 4 + pos] = acc > 0.f ? acc : 0.f;
            }
        }
    }

    // ---- phase F: pw3 + avgpool: 256oc, K=128, 4 pos ----
    {
        int oc0 = l * 4;
        const float* wbase = pw3t + (size_t)e * 32768;   // [c][256]
        float acc[4][4] = {};
        for (int c = 0; c < 128; c++) {
            float4 a = *reinterpret_cast<const float4*>(&d3[c * 4]);   // broadcast
            float4 w = *reinterpret_cast<const float4*>(wbase + c * 256 + oc0);
            float av[4] = {a.x, a.y, a.z, a.w};
            float wv[4] = {w.x, w.y, w.z, w.w};
            #pragma unroll
            for (int j = 0; j < 4; j++) {
                #pragma unroll
                for (int i = 0; i < 4; i++) acc[j][i] += wv[j] * av[i];
            }
        }
        float o4[4];
        #pragma unroll
        for (int j = 0; j < 4; j++) {
            float bb = pw3b[e * 256 + oc0 + j];
            float s = 0.f;
            #pragma unroll
            for (int i = 0; i < 4; i++) {
                float v = acc[j][i] + bb;
                s += (v > 0.f ? v : 0.f);
            }
            o4[j] = 0.25f * s;
        }
        *reinterpret_cast<float4*>(slot + (size_t)pslot * 256 + oc0) =
            make_float4(o4[0], o4[1], o4[2], o4[3]);
    }
}

// ---------------- K4: weighted combine + transpose to [B,D,16,16] ----------------
__global__ __launch_bounds__(256) void k4_comb(
    const float* __restrict__ slot, const float* __restrict__ route_w,
    float* __restrict__ out)
{
    __shared__ float cl[16][257];
    int bx = blockIdx.x;              // 0..511
    int b = bx >> 4; int hp = bx & 15;
    int tid = threadIdx.x;
    int d = tid;                      // 0..255
    for (int wp = 0; wp < 16; wp++) {
        int n = (b * 16 + hp) * 16 + wp;
        float w0 = route_w[n * 2], w1 = route_w[n * 2 + 1];
        float v = w0 * slot[(size_t)(n * 2) * 256 + d] + w1 * slot[(size_t)(n * 2 + 1) * 256 + d];
        cl[wp][d] = v;
    }
    __syncthreads();
    int wp = tid & 15; int dg = tid >> 4;
    for (int r = 0; r < 16; r++) {
        int dd = r * 16 + dg;
        out[(((size_t)b * 256 + dd) * 16 + hp) * 16 + wp] = cl[wp][dd];
    }
    if (bx == 0 && tid == 0) out[(size_t)BN * 256] = 0.0f;  // load_balance_loss
}

extern "C" void kernel_launch(void* const* d_in, const int* in_sizes, int n_in,
                              void* d_out, int out_size, void* d_ws, size_t ws_size,
                              hipStream_t stream)
{
    const float* x    = (const float*)d_in[0];
    const float* gw1  = (const float*)d_in[1];
    const float* gb1  = (const float*)d_in[2];
    const float* gw2  = (const float*)d_in[3];
    const float* gb2  = (const float*)d_in[4];
    const float* dw1w = (const float*)d_in[5];
    const float* dw1b = (const float*)d_in[6];
    const float* pw1w = (const float*)d_in[7];
    const float* pw1b = (const float*)d_in[8];
    const float* dw2w = (const float*)d_in[9];
    const float* dw2b = (const float*)d_in[10];
    const float* pw2w = (const float*)d_in[11];
    const float* pw2b = (const float*)d_in[12];
    const float* dw3w = (const float*)d_in[13];
    const float* dw3b = (const float*)d_in[14];
    const float* pw3w = (const float*)d_in[15];
    const float* pw3b = (const float*)d_in[16];

    char* ws = (char*)d_ws;
    int*   route_i = (int*)(ws + O_ROUTE_I);
    float* route_w = (float*)(ws + O_ROUTE_W);
    int*   counts  = (int*)(ws + O_COUNTS);
    int*   lists   = (int*)(ws + O_LISTS);
    float* pw2t    = (float*)(ws + O_PW2T);
    float* pw3t    = (float*)(ws + O_PW3T);
    float* slot    = (float*)(ws + O_SLOT);
    float* out     = (float*)d_out;

    hipLaunchKernelGGL(k0_prep, dim3(256), dim3(256), 0, stream,
                       pw2w, pw3w, pw2t, pw3t, counts);
    hipLaunchKernelGGL(k1_gate, dim3(BN / 32), dim3(256), 0, stream,
                       x, gw1, gb1, gw2, gb2, route_i, route_w, counts, lists);
    hipLaunchKernelGGL(k23_expert, dim3(8 * 2048), dim3(256), 0, stream,
                       x, counts, lists, dw1w, dw1b, pw1w, pw1b, dw2w, dw2b,
                       pw2t, pw2b, dw3w, dw3b, pw3t, pw3b, slot);
    hipLaunchKernelGGL(k4_comb, dim3(512), dim3(256), 0, stream,
                       slot, route_w, out);
}

// Round 5
// 532.029 us; speedup vs baseline: 1.0875x; 1.0875x over previous
//
#include <hip/hip_runtime.h>

#define BN 8192
#define GIN 768

// ---- ws layout (bytes), total ~18.5 MB ----
#define O_ROUTE_I 0UL                                   // int[BN][2]
#define O_ROUTE_W (O_ROUTE_I + (size_t)BN*2*4)          // float[BN][2]
#define O_COUNTS  (O_ROUTE_W + (size_t)BN*2*4)          // int[8] (padded to 256B)
#define O_LISTS   (O_COUNTS + 256)                      // int[8][BN]
#define O_PW2T    (O_LISTS + (size_t)8*BN*4)            // float[8][64][128]
#define O_PW3T    (O_PW2T + (size_t)8*64*128*4)         // float[8][128][256]
#define O_SLOT    (O_PW3T + (size_t)8*128*256*4)        // float[2*BN][256]

// ---------------- K0: weight transpose + zero counters ----------------
__global__ __launch_bounds__(256) void k0_prep(const float* __restrict__ pw2w,
                                               const float* __restrict__ pw3w,
                                               float* __restrict__ pw2t,
                                               float* __restrict__ pw3t,
                                               int* __restrict__ counts)
{
    int tid = blockIdx.x * 256 + threadIdx.x;
    if (tid < 8) counts[tid] = 0;
    // pw2_w: [8][128][64] -> pw2t: [8][64][128]
    for (int idx = tid; idx < 8 * 128 * 64; idx += 256 * 256) {
        int e = idx >> 13; int r = idx & 8191; int oc = r >> 6; int c = r & 63;
        pw2t[(size_t)e * 8192 + c * 128 + oc] = pw2w[idx];
    }
    // pw3_w: [8][256][128] -> pw3t: [8][128][256]
    for (int idx = tid; idx < 8 * 256 * 128; idx += 256 * 256) {
        int e = idx >> 15; int r = idx & 32767; int oc = r >> 7; int c = r & 127;
        pw3t[(size_t)e * 32768 + c * 256 + oc] = pw3w[idx];
    }
}

// ---------------- K1: gate GEMM + top2 + list build ----------------
// grid 256 blocks x 256 thr; tile = 32 patches x 128 hidden, Kc=32
__global__ __launch_bounds__(256) void k1_gate(
    const float* __restrict__ x, const float* __restrict__ w1,
    const float* __restrict__ b1, const float* __restrict__ w2,
    const float* __restrict__ b2,
    int* __restrict__ route_i, float* __restrict__ route_w,
    int* __restrict__ counts, int* __restrict__ lists)
{
    __shared__ __align__(16) float A[32][44];    // [k][p]
    __shared__ __align__(16) float Wl[32][132];  // [k][h]
    __shared__ float hl[32][132];
    __shared__ float ll[32][8];

    int tid = threadIdx.x;
    int pblk = blockIdx.x * 32;

    int pgrp = tid & 7;        // p0 = pgrp*4
    int hgrp = tid >> 3;       // h0 = hgrp*4 (0..127)
    float acc[4][4] = {};

    // staging roles
    int sp  = tid >> 3;        // patch-local 0..31 (A staging)
    int sk4 = (tid & 7) * 4;   // k offset 0..28
    int swh = tid >> 1;        // h 0..127 (W staging)
    int swk = (tid & 1) * 16;  // k offset 0 / 16

    int patchA = pblk + sp;
    int bA = patchA >> 8; int nA = patchA & 255; int hpA = nA >> 4; int wpA = nA & 15;

    for (int kc = 0; kc < GIN; kc += 32) {
        // stage A (32p x 32k), transposed to [k][p]
        {
            int k = kc + sk4;
            int c = k >> 8; int rem = k & 255; int ri = rem >> 4; int j = rem & 15;
            const float* src = x + (((size_t)(bA * 3 + c) * 256 + hpA * 16 + ri) * 256 + wpA * 16 + j);
            float4 a4 = *reinterpret_cast<const float4*>(src);
            A[sk4 + 0][sp] = a4.x; A[sk4 + 1][sp] = a4.y;
            A[sk4 + 2][sp] = a4.z; A[sk4 + 3][sp] = a4.w;
        }
        // stage W (128h x 32k), transposed to [k][h]
        {
            const float* wsrc = w1 + (size_t)swh * GIN + kc + swk;
            #pragma unroll
            for (int q = 0; q < 4; q++) {
                float4 w4 = *reinterpret_cast<const float4*>(wsrc + q * 4);
                Wl[swk + q * 4 + 0][swh] = w4.x; Wl[swk + q * 4 + 1][swh] = w4.y;
                Wl[swk + q * 4 + 2][swh] = w4.z; Wl[swk + q * 4 + 3][swh] = w4.w;
            }
        }
        __syncthreads();
        float cacc[4][4] = {};   // per-chunk partial (reduces rounding error)
        #pragma unroll
        for (int k2 = 0; k2 < 32; k2++) {
            float4 av = *reinterpret_cast<const float4*>(&A[k2][pgrp * 4]);
            float4 wv = *reinterpret_cast<const float4*>(&Wl[k2][hgrp * 4]);
            float aa[4] = {av.x, av.y, av.z, av.w};
            float ww[4] = {wv.x, wv.y, wv.z, wv.w};
            #pragma unroll
            for (int i = 0; i < 4; i++) {
                #pragma unroll
                for (int jj = 0; jj < 4; jj++) cacc[i][jj] += aa[i] * ww[jj];
            }
        }
        #pragma unroll
        for (int i = 0; i < 4; i++) {
            #pragma unroll
            for (int jj = 0; jj < 4; jj++) acc[i][jj] += cacc[i][jj];
        }
        __syncthreads();
    }

    // h = relu(acc + b1) -> hl
    #pragma unroll
    for (int jj = 0; jj < 4; jj++) {
        float bb = b1[hgrp * 4 + jj];
        #pragma unroll
        for (int i = 0; i < 4; i++) {
            float v = acc[i][jj] + bb;
            hl[pgrp * 4 + i][hgrp * 4 + jj] = v > 0.f ? v : 0.f;
        }
    }
    __syncthreads();

    // logits: 32p x 8e
    {
        int lp = tid >> 3; int le = tid & 7;
        float lacc = b2[le];
        const float* wrow = w2 + le * 128;
        for (int h = 0; h < 128; h++) lacc += hl[lp][h] * wrow[h];
        ll[lp][le] = lacc;
    }
    __syncthreads();

    if (tid < 32) {
        int patch = pblk + tid;
        float v[8];
        #pragma unroll
        for (int e = 0; e < 8; e++) v[e] = ll[tid][e];
        // top-2, ties -> lower index (matches lax.top_k)
        int e0 = 0; float m0 = v[0];
        #pragma unroll
        for (int e = 1; e < 8; e++) if (v[e] > m0) { m0 = v[e]; e0 = e; }
        int e1 = -1; float m1 = -3.0e38f;
        #pragma unroll
        for (int e = 0; e < 8; e++) if (e != e0 && v[e] > m1) { m1 = v[e]; e1 = e; }
        float t = expf(m1 - m0);       // m0 is the max
        float w0 = 1.f / (1.f + t);
        float w1v = t * w0;
        route_i[patch * 2] = e0; route_i[patch * 2 + 1] = e1;
        route_w[patch * 2] = w0; route_w[patch * 2 + 1] = w1v;
        int p0 = atomicAdd(&counts[e0], 1);
        lists[e0 * BN + p0] = patch * 2;
        int p1 = atomicAdd(&counts[e1], 1);
        lists[e1 * BN + p1] = patch * 2 + 1;
    }
}

// ---------------- K23: full expert pipeline, expert-binned, 4 entries/block ----------
// BARRIER-FREE: each wave owns one entry end-to-end; all LDS traffic is
// wave-private. LDS = 4 x 2560 floats = 40960 B -> 4 blocks/CU.
// Phase C uses a STREAMING 3-row window (rc/re/ro, 24 floats) instead of a
// p1r[64] private array -- round-4's VGPR spill (FETCH/WRITE +116MB scratch
// traffic at VGPR_Count=64) came from that array under the (256,4) cap.
// Per-entry LDS slice (floats), time-multiplexed:
//   pl  @0     [3][16][20] =  960   (A write, B read)
//   d1  @2048  [3][64]     =  192   (B write, C read)
//   d2t @0     [16][68]    = 1088   (C write, D read)  aliases dead pl
//   p2  @0     [128][16]sw = 2048   (D write, E read)  aliases d2t (D-reads
//                                    precede D-writes in program order)
//   d3  @2048  [128][4]    =  512   (E write, F read)  aliases dead d1
// p2 swizzle: addr = ch*16 + ((pos + (ch>>3)) & 15)
__global__ __launch_bounds__(256, 4) void k23_expert(
    const float* __restrict__ x, const int* __restrict__ counts,
    const int* __restrict__ lists,
    const float* __restrict__ dw1w, const float* __restrict__ dw1b,
    const float* __restrict__ pw1w, const float* __restrict__ pw1b,
    const float* __restrict__ dw2w, const float* __restrict__ dw2b,
    const float* __restrict__ pw2t, const float* __restrict__ pw2b,
    const float* __restrict__ dw3w, const float* __restrict__ dw3b,
    const float* __restrict__ pw3t, const float* __restrict__ pw3b,
    float* __restrict__ slot)
{
    __shared__ __align__(16) float buf[4][2560];

    int e = blockIdx.x & 7;
    int chunk = blockIdx.x >> 3;
    int cnt = counts[e];
    int base = chunk * 4;
    if (base >= cnt) return;
    int tid = threadIdx.x;
    int en = tid >> 6; int l = tid & 63;       // one wave per entry
    if (base + en >= cnt) return;              // wave-uniform exit
    int pslot = lists[e * BN + base + en];     // wave-uniform scalar load
    int patch = pslot >> 1;
    int b = patch >> 8, nn = patch & 255, hp = nn >> 4, wp = nn & 15;

    float* pl  = buf[en];
    float* d1  = buf[en] + 2048;
    float* d2t = buf[en];
    float* p2  = buf[en];
    float* d3  = buf[en] + 2048;

    // ---- phase A: stage patch [3][16][20] ----
    {
        int r = l >> 2; int j4 = (l & 3) * 4;
        #pragma unroll
        for (int c = 0; c < 3; c++) {
            const float* src = x + (((size_t)(b * 3 + c) * 256 + hp * 16 + r) * 256 + wp * 16 + j4);
            float4 v = *reinterpret_cast<const float4*>(src);
            *reinterpret_cast<float4*>(&pl[c * 320 + r * 20 + j4]) = v;
        }
    }

    // ---- phase B: dw1 3ch x 8x8 ----
    {
        int oh = l >> 3, ow = l & 7;
        #pragma unroll
        for (int c = 0; c < 3; c++) {
            const float* w9 = dw1w + (e * 3 + c) * 9;
            float acc = dw1b[e * 3 + c];
            #pragma unroll
            for (int ki = 0; ki < 3; ki++) {
                int ih = oh * 2 - 1 + ki;
                if ((unsigned)ih < 16u) {
                    #pragma unroll
                    for (int kj = 0; kj < 3; kj++) {
                        int iw = ow * 2 - 1 + kj;
                        if ((unsigned)iw < 16u) acc += pl[c * 320 + ih * 20 + iw] * w9[ki * 3 + kj];
                    }
                }
            }
            d1[c * 64 + l] = acc > 0.f ? acc : 0.f;
        }
    }

    // ---- phase C: pw1 (64oc, K=3) fused with dw2, streaming 3-row window ----
    // Identical per-element arithmetic to the reference order:
    //   p1 = relu(pb + a0*pw0 + a1*pw1 + a2*pw2)
    //   dw2 acc over ki=0,1,2 (rows 2oh-1, 2oh, 2oh+1), kj=0..2
    {
        const float* w3 = pw1w + (e * 64 + l) * 3;
        float pw0 = w3[0], pw1v = w3[1], pw2v = w3[2];
        float pb = pw1b[e * 64 + l];
        const float* w9 = dw2w + (e * 64 + l) * 9;
        float wd[9];
        #pragma unroll
        for (int i = 0; i < 9; i++) wd[i] = w9[i];
        float bd = dw2b[e * 64 + l];

        float rc[8] = {};   // carry row (ih = 2oh-1); never read when oh==0
        float re[8], ro[8];

        #pragma unroll
        for (int oh = 0; oh < 4; oh++) {
            // compute pw1 rows ih=2oh (re) and ih=2oh+1 (ro), 8 positions each
            #pragma unroll
            for (int half = 0; half < 2; half++) {
                float* dst = half ? ro : re;
                const float* d1b = d1 + (oh * 2 + half) * 8;
                float4 x0 = *reinterpret_cast<const float4*>(&d1b[0]);
                float4 x1 = *reinterpret_cast<const float4*>(&d1b[4]);
                float4 y0 = *reinterpret_cast<const float4*>(&d1b[64]);
                float4 y1 = *reinterpret_cast<const float4*>(&d1b[68]);
                float4 z0 = *reinterpret_cast<const float4*>(&d1b[128]);
                float4 z1 = *reinterpret_cast<const float4*>(&d1b[132]);
                float v;
                v = pb + x0.x * pw0 + y0.x * pw1v + z0.x * pw2v; dst[0] = v > 0.f ? v : 0.f;
                v = pb + x0.y * pw0 + y0.y * pw1v + z0.y * pw2v; dst[1] = v > 0.f ? v : 0.f;
                v = pb + x0.z * pw0 + y0.z * pw1v + z0.z * pw2v; dst[2] = v > 0.f ? v : 0.f;
                v = pb + x0.w * pw0 + y0.w * pw1v + z0.w * pw2v; dst[3] = v > 0.f ? v : 0.f;
                v = pb + x1.x * pw0 + y1.x * pw1v + z1.x * pw2v; dst[4] = v > 0.f ? v : 0.f;
                v = pb + x1.y * pw0 + y1.y * pw1v + z1.y * pw2v; dst[5] = v > 0.f ? v : 0.f;
                v = pb + x1.z * pw0 + y1.z * pw1v + z1.z * pw2v; dst[6] = v > 0.f ? v : 0.f;
                v = pb + x1.w * pw0 + y1.w * pw1v + z1.w * pw2v; dst[7] = v > 0.f ? v : 0.f;
            }
            // dw2 output row oh (4 positions), then write d2t[pos][ch]
            #pragma unroll
            for (int ow = 0; ow < 4; ow++) {
                float acc = bd;
                if (oh > 0) {                      // ki=0: row 2oh-1 (rc)
                    #pragma unroll
                    for (int kj = 0; kj < 3; kj++) {
                        int iw = ow * 2 - 1 + kj;
                        if ((unsigned)iw < 8u) acc += rc[iw] * wd[kj];
                    }
                }
                #pragma unroll
                for (int kj = 0; kj < 3; kj++) {   // ki=1: row 2oh (re)
                    int iw = ow * 2 - 1 + kj;
                    if ((unsigned)iw < 8u) acc += re[iw] * wd[3 + kj];
                }
                #pragma unroll
                for (int kj = 0; kj < 3; kj++) {   // ki=2: row 2oh+1 (ro)
                    int iw = ow * 2 - 1 + kj;
                    if ((unsigned)iw < 8u) acc += ro[iw] * wd[6 + kj];
                }
                d2t[(oh * 4 + ow) * 68 + l] = acc > 0.f ? acc : 0.f;
            }
            #pragma unroll
            for (int i = 0; i < 8; i++) rc[i] = ro[i];   // rotate window
        }
    }

    // ---- phase D: pw2 128oc x 16pos, K=64 (reads d2t, then writes p2) ----
    {
        int ocg = l & 15; int pq = l >> 4;
        int oc0 = ocg * 8; int p0 = pq * 4;
        float acc[8][4] = {};
        const float* wbase = pw2t + (size_t)e * 8192;   // [c][128]
        for (int c4 = 0; c4 < 16; c4++) {
            float4 a0 = *reinterpret_cast<const float4*>(&d2t[(p0 + 0) * 68 + c4 * 4]);
            float4 a1 = *reinterpret_cast<const float4*>(&d2t[(p0 + 1) * 68 + c4 * 4]);
            float4 a2 = *reinterpret_cast<const float4*>(&d2t[(p0 + 2) * 68 + c4 * 4]);
            float4 a3 = *reinterpret_cast<const float4*>(&d2t[(p0 + 3) * 68 + c4 * 4]);
            float av[4][4] = {{a0.x, a1.x, a2.x, a3.x}, {a0.y, a1.y, a2.y, a3.y},
                              {a0.z, a1.z, a2.z, a3.z}, {a0.w, a1.w, a2.w, a3.w}};
            #pragma unroll
            for (int cc = 0; cc < 4; cc++) {
                int c = c4 * 4 + cc;
                float4 wa = *reinterpret_cast<const float4*>(wbase + c * 128 + oc0);
                float4 wb = *reinterpret_cast<const float4*>(wbase + c * 128 + oc0 + 4);
                float wv[8] = {wa.x, wa.y, wa.z, wa.w, wb.x, wb.y, wb.z, wb.w};
                #pragma unroll
                for (int j = 0; j < 8; j++) {
                    #pragma unroll
                    for (int i = 0; i < 4; i++) acc[j][i] += wv[j] * av[cc][i];
                }
            }
        }
        #pragma unroll
        for (int j = 0; j < 8; j++) {
            float bb = pw2b[e * 128 + oc0 + j];
            #pragma unroll
            for (int i = 0; i < 4; i++) {
                float v = acc[j][i] + bb;
                // swizzled store: ch = oc0+j, pos = p0+i, ch>>3 == ocg
                p2[(oc0 + j) * 16 + ((p0 + i + ocg) & 15)] = v > 0.f ? v : 0.f;
            }
        }
    }

    // ---- phase E: dw3 128ch x 2x2 (reads swizzled p2) ----
    {
        #pragma unroll
        for (int chb = 0; chb < 128; chb += 64) {
            int ch = chb + l;
            int grp = ch >> 3;
            const float* w9 = dw3w + (e * 128 + ch) * 9;
            float bb = dw3b[e * 128 + ch];
            #pragma unroll
            for (int pos = 0; pos < 4; pos++) {
                int oh = pos >> 1, ow = pos & 1;
                float acc = bb;
                #pragma unroll
                for (int ki = 0; ki < 3; ki++) {
                    int ih = oh * 2 - 1 + ki;
                    if ((unsigned)ih < 4u) {
                        #pragma unroll
                        for (int kj = 0; kj < 3; kj++) {
                            int iw = ow * 2 - 1 + kj;
                            if ((unsigned)iw < 4u)
                                acc += p2[ch * 16 + ((ih * 4 + iw + grp) & 15)] * w9[ki * 3 + kj];
                        }
                    }
                }
                d3[ch * 4 + pos] = acc > 0.f ? acc : 0.f;
            }
        }
    }

    // ---- phase F: pw3 + avgpool: 256oc, K=128, 4 pos ----
    {
        int oc0 = l * 4;
        const float* wbase = pw3t + (size_t)e * 32768;   // [c][256]
        float acc[4][4] = {};
        for (int c = 0; c < 128; c++) {
            float4 a = *reinterpret_cast<const float4*>(&d3[c * 4]);   // broadcast
            float4 w = *reinterpret_cast<const float4*>(wbase + c * 256 + oc0);
            float av[4] = {a.x, a.y, a.z, a.w};
            float wv[4] = {w.x, w.y, w.z, w.w};
            #pragma unroll
            for (int j = 0; j < 4; j++) {
                #pragma unroll
                for (int i = 0; i < 4; i++) acc[j][i] += wv[j] * av[i];
            }
        }
        float o4[4];
        #pragma unroll
        for (int j = 0; j < 4; j++) {
            float bb = pw3b[e * 256 + oc0 + j];
            float s = 0.f;
            #pragma unroll
            for (int i = 0; i < 4; i++) {
                float v = acc[j][i] + bb;
                s += (v > 0.f ? v : 0.f);
            }
            o4[j] = 0.25f * s;
        }
        *reinterpret_cast<float4*>(slot + (size_t)pslot * 256 + oc0) =
            make_float4(o4[0], o4[1], o4[2], o4[3]);
    }
}

// ---------------- K4: weighted combine + transpose to [B,D,16,16] ----------------
__global__ __launch_bounds__(256) void k4_comb(
    const float* __restrict__ slot, const float* __restrict__ route_w,
    float* __restrict__ out)
{
    __shared__ float cl[16][257];
    int bx = blockIdx.x;              // 0..511
    int b = bx >> 4; int hp = bx & 15;
    int tid = threadIdx.x;
    int d = tid;                      // 0..255
    for (int wp = 0; wp < 16; wp++) {
        int n = (b * 16 + hp) * 16 + wp;
        float w0 = route_w[n * 2], w1 = route_w[n * 2 + 1];
        float v = w0 * slot[(size_t)(n * 2) * 256 + d] + w1 * slot[(size_t)(n * 2 + 1) * 256 + d];
        cl[wp][d] = v;
    }
    __syncthreads();
    int wp = tid & 15; int dg = tid >> 4;
    for (int r = 0; r < 16; r++) {
        int dd = r * 16 + dg;
        out[(((size_t)b * 256 + dd) * 16 + hp) * 16 + wp] = cl[wp][dd];
    }
    if (bx == 0 && tid == 0) out[(size_t)BN * 256] = 0.0f;  // load_balance_loss
}

extern "C" void kernel_launch(void* const* d_in, const int* in_sizes, int n_in,
                              void* d_out, int out_size, void* d_ws, size_t ws_size,
                              hipStream_t stream)
{
    const float* x    = (const float*)d_in[0];
    const float* gw1  = (const float*)d_in[1];
    const float* gb1  = (const float*)d_in[2];
    const float* gw2  = (const float*)d_in[3];
    const float* gb2  = (const float*)d_in[4];
    const float* dw1w = (const float*)d_in[5];
    const float* dw1b = (const float*)d_in[6];
    const float* pw1w = (const float*)d_in[7];
    const float* pw1b = (const float*)d_in[8];
    const float* dw2w = (const float*)d_in[9];
    const float* dw2b = (const float*)d_in[10];
    const float* pw2w = (const float*)d_in[11];
    const float* pw2b = (const float*)d_in[12];
    const float* dw3w = (const float*)d_in[13];
    const float* dw3b = (const float*)d_in[14];
    const float* pw3w = (const float*)d_in[15];
    const float* pw3b = (const float*)d_in[16];

    char* ws = (char*)d_ws;
    int*   route_i = (int*)(ws + O_ROUTE_I);
    float* route_w = (float*)(ws + O_ROUTE_W);
    int*   counts  = (int*)(ws + O_COUNTS);
    int*   lists   = (int*)(ws + O_LISTS);
    float* pw2t    = (float*)(ws + O_PW2T);
    float* pw3t    = (float*)(ws + O_PW3T);
    float* slot    = (float*)(ws + O_SLOT);
    float* out     = (float*)d_out;

    hipLaunchKernelGGL(k0_prep, dim3(256), dim3(256), 0, stream,
                       pw2w, pw3w, pw2t, pw3t, counts);
    hipLaunchKernelGGL(k1_gate, dim3(BN / 32), dim3(256), 0, stream,
                       x, gw1, gb1, gw2, gb2, route_i, route_w, counts, lists);
    hipLaunchKernelGGL(k23_expert, dim3(8 * 2048), dim3(256), 0, stream,
                       x, counts, lists, dw1w, dw1b, pw1w, pw1b, dw2w, dw2b,
                       pw2t, pw2b, dw3w, dw3b, pw3t, pw3b, slot);
    hipLaunchKernelGGL(k4_comb, dim3(512), dim3(256), 0, stream,
                       slot, route_w, out);
}

// Round 7
// 520.198 us; speedup vs baseline: 1.1122x; 1.0227x over previous
//
#include <hip/hip_runtime.h>

#define BN 8192
#define GIN 768
#define SL 2560   // per-entry LDS slice (floats)

// ---- ws layout (bytes), total ~18.5 MB ----
#define O_ROUTE_I 0UL                                   // int[BN][2]
#define O_ROUTE_W (O_ROUTE_I + (size_t)BN*2*4)          // float[BN][2]
#define O_COUNTS  (O_ROUTE_W + (size_t)BN*2*4)          // int[8] (padded to 256B)
#define O_LISTS   (O_COUNTS + 256)                      // int[8][BN]
#define O_PW2T    (O_LISTS + (size_t)8*BN*4)            // float[8][64][128]
#define O_PW3T    (O_PW2T + (size_t)8*64*128*4)         // float[8][128][256]
#define O_SLOT    (O_PW3T + (size_t)8*128*256*4)        // float[2*BN][256]

// ---------------- K0: weight transpose + zero counters ----------------
__global__ __launch_bounds__(256) void k0_prep(const float* __restrict__ pw2w,
                                               const float* __restrict__ pw3w,
                                               float* __restrict__ pw2t,
                                               float* __restrict__ pw3t,
                                               int* __restrict__ counts)
{
    int tid = blockIdx.x * 256 + threadIdx.x;
    if (tid < 8) counts[tid] = 0;
    for (int idx = tid; idx < 8 * 128 * 64; idx += 256 * 256) {
        int e = idx >> 13; int r = idx & 8191; int oc = r >> 6; int c = r & 63;
        pw2t[(size_t)e * 8192 + c * 128 + oc] = pw2w[idx];
    }
    for (int idx = tid; idx < 8 * 256 * 128; idx += 256 * 256) {
        int e = idx >> 15; int r = idx & 32767; int oc = r >> 7; int c = r & 127;
        pw3t[(size_t)e * 32768 + c * 256 + oc] = pw3w[idx];
    }
}

// ---------------- K1: gate GEMM + top2 + list build ----------------
// grid 512 blocks (2/CU); tile = 16 patches x 128 hidden, Kc=32.
// Per-output k-summation order identical to previous version (bit-exact logits).
__global__ __launch_bounds__(256) void k1_gate(
    const float* __restrict__ x, const float* __restrict__ w1,
    const float* __restrict__ b1, const float* __restrict__ w2,
    const float* __restrict__ b2,
    int* __restrict__ route_i, float* __restrict__ route_w,
    int* __restrict__ counts, int* __restrict__ lists)
{
    __shared__ __align__(16) float A[32][20];    // [k][p]
    __shared__ __align__(16) float Wl[32][132];  // [k][h]
    __shared__ float hl[16][132];
    __shared__ float ll[16][8];

    int tid = threadIdx.x;
    int pblk = blockIdx.x * 16;

    int pgrp = tid & 7;        // p0 = pgrp*2
    int hgrp = tid >> 3;       // h0 = hgrp*4 (0..124)
    float acc[2][4] = {};

    int sp  = tid >> 4;        // patch-local 0..15 (A staging)
    int sk2 = (tid & 15) * 2;  // k offset 0..30
    int swh = tid >> 1;        // h 0..127 (W staging)
    int swk = (tid & 1) * 16;  // k offset 0 / 16

    int patchA = pblk + sp;
    int bA = patchA >> 8; int nA = patchA & 255; int hpA = nA >> 4; int wpA = nA & 15;

    for (int kc = 0; kc < GIN; kc += 32) {
        // stage A (16p x 32k) transposed to [k][p]; k,k+1 share an x row (sk2 even)
        {
            int k = kc + sk2;
            int c = k >> 8; int rem = k & 255; int ri = rem >> 4; int j = rem & 15;
            const float* src = x + (((size_t)(bA * 3 + c) * 256 + hpA * 16 + ri) * 256 + wpA * 16 + j);
            float2 a2 = *reinterpret_cast<const float2*>(src);
            A[sk2][sp] = a2.x; A[sk2 + 1][sp] = a2.y;
        }
        // stage W (128h x 32k) transposed to [k][h]
        {
            const float* wsrc = w1 + (size_t)swh * GIN + kc + swk;
            #pragma unroll
            for (int qq = 0; qq < 4; qq++) {
                float4 w4 = *reinterpret_cast<const float4*>(wsrc + qq * 4);
                Wl[swk + qq * 4 + 0][swh] = w4.x; Wl[swk + qq * 4 + 1][swh] = w4.y;
                Wl[swk + qq * 4 + 2][swh] = w4.z; Wl[swk + qq * 4 + 3][swh] = w4.w;
            }
        }
        __syncthreads();
        float cacc[2][4] = {};
        #pragma unroll
        for (int k2 = 0; k2 < 32; k2++) {
            float2 av = *reinterpret_cast<const float2*>(&A[k2][pgrp * 2]);
            float4 wv = *reinterpret_cast<const float4*>(&Wl[k2][hgrp * 4]);
            float aa[2] = {av.x, av.y};
            float ww[4] = {wv.x, wv.y, wv.z, wv.w};
            #pragma unroll
            for (int i = 0; i < 2; i++) {
                #pragma unroll
                for (int jj = 0; jj < 4; jj++) cacc[i][jj] += aa[i] * ww[jj];
            }
        }
        #pragma unroll
        for (int i = 0; i < 2; i++) {
            #pragma unroll
            for (int jj = 0; jj < 4; jj++) acc[i][jj] += cacc[i][jj];
        }
        __syncthreads();
    }

    #pragma unroll
    for (int jj = 0; jj < 4; jj++) {
        float bb = b1[hgrp * 4 + jj];
        #pragma unroll
        for (int i = 0; i < 2; i++) {
            float v = acc[i][jj] + bb;
            hl[pgrp * 2 + i][hgrp * 4 + jj] = v > 0.f ? v : 0.f;
        }
    }
    __syncthreads();

    if (tid < 128) {
        int lp = tid >> 3; int le = tid & 7;
        float lacc = b2[le];
        const float* wrow = w2 + le * 128;
        for (int h = 0; h < 128; h++) lacc += hl[lp][h] * wrow[h];
        ll[lp][le] = lacc;
    }
    __syncthreads();

    if (tid < 16) {
        int patch = pblk + tid;
        float v[8];
        #pragma unroll
        for (int e = 0; e < 8; e++) v[e] = ll[tid][e];
        int e0 = 0; float m0 = v[0];
        #pragma unroll
        for (int e = 1; e < 8; e++) if (v[e] > m0) { m0 = v[e]; e0 = e; }
        int e1 = -1; float m1 = -3.0e38f;
        #pragma unroll
        for (int e = 0; e < 8; e++) if (e != e0 && v[e] > m1) { m1 = v[e]; e1 = e; }
        float t = expf(m1 - m0);
        float w0 = 1.f / (1.f + t);
        float w1v = t * w0;
        route_i[patch * 2] = e0; route_i[patch * 2 + 1] = e1;
        route_w[patch * 2] = w0; route_w[patch * 2 + 1] = w1v;
        int p0 = atomicAdd(&counts[e0], 1);
        lists[e0 * BN + p0] = patch * 2;
        int p1 = atomicAdd(&counts[e1], 1);
        lists[e1 * BN + p1] = patch * 2 + 1;
    }
}

// ---------------- K23: expert pipeline, 4 entries/block, weight-reuse D/F ------
// Phases A-C,E: wave wid <-> entry wid (wave-private LDS, no sync needed).
// Phases D,F:   wave wid <-> OUTPUT-CHANNEL RANGE; lane group en_l = (l>>4)
//               <-> entry. Weight addresses depend only on (wid, q) -> identical
//               across the 4 en_l groups -> coalescer merges: weights fetched
//               ONCE per block instead of once per wave (4x fewer L2 loads).
// Rotations (keep cross-entry LDS reads <=2-way, free):
//   d2t col: (ch + 4*en)&63       p2 pos: (pos + g + en)&15
//   d3  ch : (ch + 4*en)&127
// Missing entries are clamped to the last valid entry (valid dup work);
// only global stores are predicated on en < n_en.
// LDS = 4 x 2560 x 4B = 40960 B -> 4 blocks/CU.
__global__ __launch_bounds__(256, 4) void k23_expert(
    const float* __restrict__ x, const int* __restrict__ counts,
    const int* __restrict__ lists,
    const float* __restrict__ dw1w, const float* __restrict__ dw1b,
    const float* __restrict__ pw1w, const float* __restrict__ pw1b,
    const float* __restrict__ dw2w, const float* __restrict__ dw2b,
    const float* __restrict__ pw2t, const float* __restrict__ pw2b,
    const float* __restrict__ dw3w, const float* __restrict__ dw3b,
    const float* __restrict__ pw3t, const float* __restrict__ pw3b,
    float* __restrict__ slot)
{
    __shared__ __align__(16) float buf[4][SL];

    int e = blockIdx.x & 7;
    int chunk = blockIdx.x >> 3;
    int cnt = counts[e];
    int base = chunk * 4;
    if (base >= cnt) return;                   // uniform: before any barrier
    int n_en = cnt - base; if (n_en > 4) n_en = 4;
    int tid = threadIdx.x;
    int wid = tid >> 6;
    int l = tid & 63;
    int en_l = l >> 4;                         // lane-entry (phases D,F)
    int q = l & 15;

    int myidx = base + wid; if (myidx >= cnt) myidx = cnt - 1;   // clamp
    int pslot = lists[e * BN + myidx];         // wave-uniform scalar load
    int patch = pslot >> 1;
    int b = patch >> 8, nn = patch & 255, hp = nn >> 4, wp = nn & 15;

    float* pl  = buf[wid];
    float* d1  = buf[wid] + 2048;
    float* d2t = buf[wid];

    // ---- phase A: stage patch [3][16][20] ----
    {
        int r = l >> 2; int j4 = (l & 3) * 4;
        #pragma unroll
        for (int c = 0; c < 3; c++) {
            const float* src = x + (((size_t)(b * 3 + c) * 256 + hp * 16 + r) * 256 + wp * 16 + j4);
            float4 v = *reinterpret_cast<const float4*>(src);
            *reinterpret_cast<float4*>(&pl[c * 320 + r * 20 + j4]) = v;
        }
    }

    // ---- phase B: dw1 3ch x 8x8 ----
    {
        int oh = l >> 3, ow = l & 7;
        #pragma unroll
        for (int c = 0; c < 3; c++) {
            const float* w9 = dw1w + (e * 3 + c) * 9;
            float acc = dw1b[e * 3 + c];
            #pragma unroll
            for (int ki = 0; ki < 3; ki++) {
                int ih = oh * 2 - 1 + ki;
                if ((unsigned)ih < 16u) {
                    #pragma unroll
                    for (int kj = 0; kj < 3; kj++) {
                        int iw = ow * 2 - 1 + kj;
                        if ((unsigned)iw < 16u) acc += pl[c * 320 + ih * 20 + iw] * w9[ki * 3 + kj];
                    }
                }
            }
            d1[c * 64 + l] = acc > 0.f ? acc : 0.f;
        }
    }

    // ---- phase C: pw1 fused with dw2, streaming 3-row window; rotated d2t store --
    {
        const float* w3 = pw1w + (e * 64 + l) * 3;
        float pw0 = w3[0], pw1v = w3[1], pw2v = w3[2];
        float pb = pw1b[e * 64 + l];
        const float* w9 = dw2w + (e * 64 + l) * 9;
        float wd[9];
        #pragma unroll
        for (int i = 0; i < 9; i++) wd[i] = w9[i];
        float bd = dw2b[e * 64 + l];

        int dcol = (l + wid * 4) & 63;        // rotated channel column
        float rc[8] = {};
        float re[8], ro[8];

        #pragma unroll
        for (int oh = 0; oh < 4; oh++) {
            #pragma unroll
            for (int half = 0; half < 2; half++) {
                float* dst = half ? ro : re;
                const float* d1b = d1 + (oh * 2 + half) * 8;
                float4 x0 = *reinterpret_cast<const float4*>(&d1b[0]);
                float4 x1 = *reinterpret_cast<const float4*>(&d1b[4]);
                float4 y0 = *reinterpret_cast<const float4*>(&d1b[64]);
                float4 y1 = *reinterpret_cast<const float4*>(&d1b[68]);
                float4 z0 = *reinterpret_cast<const float4*>(&d1b[128]);
                float4 z1 = *reinterpret_cast<const float4*>(&d1b[132]);
                float v;
                v = pb + x0.x * pw0 + y0.x * pw1v + z0.x * pw2v; dst[0] = v > 0.f ? v : 0.f;
                v = pb + x0.y * pw0 + y0.y * pw1v + z0.y * pw2v; dst[1] = v > 0.f ? v : 0.f;
                v = pb + x0.z * pw0 + y0.z * pw1v + z0.z * pw2v; dst[2] = v > 0.f ? v : 0.f;
                v = pb + x0.w * pw0 + y0.w * pw1v + z0.w * pw2v; dst[3] = v > 0.f ? v : 0.f;
                v = pb + x1.x * pw0 + y1.x * pw1v + z1.x * pw2v; dst[4] = v > 0.f ? v : 0.f;
                v = pb + x1.y * pw0 + y1.y * pw1v + z1.y * pw2v; dst[5] = v > 0.f ? v : 0.f;
                v = pb + x1.z * pw0 + y1.z * pw1v + z1.z * pw2v; dst[6] = v > 0.f ? v : 0.f;
                v = pb + x1.w * pw0 + y1.w * pw1v + z1.w * pw2v; dst[7] = v > 0.f ? v : 0.f;
            }
            #pragma unroll
            for (int ow = 0; ow < 4; ow++) {
                float acc = bd;
                if (oh > 0) {
                    #pragma unroll
                    for (int kj = 0; kj < 3; kj++) {
                        int iw = ow * 2 - 1 + kj;
                        if ((unsigned)iw < 8u) acc += rc[iw] * wd[kj];
                    }
                }
                #pragma unroll
                for (int kj = 0; kj < 3; kj++) {
                    int iw = ow * 2 - 1 + kj;
                    if ((unsigned)iw < 8u) acc += re[iw] * wd[3 + kj];
                }
                #pragma unroll
                for (int kj = 0; kj < 3; kj++) {
                    int iw = ow * 2 - 1 + kj;
                    if ((unsigned)iw < 8u) acc += ro[iw] * wd[6 + kj];
                }
                d2t[(oh * 4 + ow) * 68 + dcol] = acc > 0.f ? acc : 0.f;
            }
            #pragma unroll
            for (int i = 0; i < 8; i++) rc[i] = ro[i];
        }
    }
    __syncthreads();   // all entries' d2t complete

    // ---- phase D: pw2. wave wid -> oc range wid*32..+31; lane group en_l -> entry.
    {
        const float* dsl = buf[en_l];
        int ocg = q & 3, pq = q >> 2;
        int oc0 = wid * 32 + ocg * 8;
        int p0 = pq * 4;
        float acc[8][4] = {};
        const float* wbase = pw2t + (size_t)e * 8192;   // [c][128]
        #pragma unroll 2
        for (int c4 = 0; c4 < 16; c4++) {
            int col = (c4 * 4 + en_l * 4) & 63;
            float4 a0 = *reinterpret_cast<const float4*>(&dsl[(p0 + 0) * 68 + col]);
            float4 a1 = *reinterpret_cast<const float4*>(&dsl[(p0 + 1) * 68 + col]);
            float4 a2 = *reinterpret_cast<const float4*>(&dsl[(p0 + 2) * 68 + col]);
            float4 a3 = *reinterpret_cast<const float4*>(&dsl[(p0 + 3) * 68 + col]);
            float av[4][4] = {{a0.x, a1.x, a2.x, a3.x}, {a0.y, a1.y, a2.y, a3.y},
                              {a0.z, a1.z, a2.z, a3.z}, {a0.w, a1.w, a2.w, a3.w}};
            #pragma unroll
            for (int cc = 0; cc < 4; cc++) {
                int c = c4 * 4 + cc;
                float4 wa = *reinterpret_cast<const float4*>(wbase + c * 128 + oc0);
                float4 wb = *reinterpret_cast<const float4*>(wbase + c * 128 + oc0 + 4);
                float wv[8] = {wa.x, wa.y, wa.z, wa.w, wb.x, wb.y, wb.z, wb.w};
                #pragma unroll
                for (int j = 0; j < 8; j++) {
                    #pragma unroll
                    for (int i = 0; i < 4; i++) acc[j][i] += wv[j] * av[cc][i];
                }
            }
        }
        __syncthreads();   // all d2t reads done before p2 stores (alias @0)
        int g = oc0 >> 3;
        float* p2w = buf[en_l];
        #pragma unroll
        for (int j = 0; j < 8; j++) {
            float bb = pw2b[e * 128 + oc0 + j];
            #pragma unroll
            for (int i = 0; i < 4; i++) {
                float v = acc[j][i] + bb;
                p2w[(oc0 + j) * 16 + ((p0 + i + g + en_l) & 15)] = v > 0.f ? v : 0.f;
            }
        }
    }
    __syncthreads();   // p2 complete

    // ---- phase E: dw3 128ch x 2x2 (wave-entry wid; reads rotated p2) ----
    {
        float* p2 = buf[wid];
        float* d3 = buf[wid] + 2048;
        #pragma unroll
        for (int chb = 0; chb < 128; chb += 64) {
            int ch = chb + l;
            int grp = ch >> 3;
            const float* w9 = dw3w + (e * 128 + ch) * 9;
            float bb = dw3b[e * 128 + ch];
            #pragma unroll
            for (int pos = 0; pos < 4; pos++) {
                int oh = pos >> 1, ow = pos & 1;
                float acc = bb;
                #pragma unroll
                for (int ki = 0; ki < 3; ki++) {
                    int ih = oh * 2 - 1 + ki;
                    if ((unsigned)ih < 4u) {
                        #pragma unroll
                        for (int kj = 0; kj < 3; kj++) {
                            int iw = ow * 2 - 1 + kj;
                            if ((unsigned)iw < 4u)
                                acc += p2[ch * 16 + ((ih * 4 + iw + grp + wid) & 15)] * w9[ki * 3 + kj];
                        }
                    }
                }
                d3[((ch + wid * 4) & 127) * 4 + pos] = acc > 0.f ? acc : 0.f;
            }
        }
    }
    __syncthreads();   // all entries' d3 complete

    // ---- phase F: pw3 + avgpool. wave wid -> oc range wid*64..+63; en_l -> entry.
    {
        int oc0 = wid * 64 + q * 4;
        const float* d3b = buf[en_l] + 2048;
        const float* wbase = pw3t + (size_t)e * 32768;   // [c][256]
        float acc[4][4] = {};
        #pragma unroll 4
        for (int c = 0; c < 128; c++) {
            float4 a = *reinterpret_cast<const float4*>(&d3b[((c + en_l * 4) & 127) * 4]);
            float4 w = *reinterpret_cast<const float4*>(wbase + c * 256 + oc0);
            float av[4] = {a.x, a.y, a.z, a.w};
            float wv[4] = {w.x, w.y, w.z, w.w};
            #pragma unroll
            for (int j = 0; j < 4; j++) {
                #pragma unroll
                for (int i = 0; i < 4; i++) acc[j][i] += wv[j] * av[i];
            }
        }
        if (en_l < n_en) {
            int ps_f = lists[e * BN + base + en_l];     // L2-hot re-load
            float o4[4];
            #pragma unroll
            for (int j = 0; j < 4; j++) {
                float bb = pw3b[e * 256 + oc0 + j];
                float s = 0.f;
                #pragma unroll
                for (int i = 0; i < 4; i++) {
                    float v = acc[j][i] + bb;
                    s += (v > 0.f ? v : 0.f);
                }
                o4[j] = 0.25f * s;
            }
            *reinterpret_cast<float4*>(slot + (size_t)ps_f * 256 + oc0) =
                make_float4(o4[0], o4[1], o4[2], o4[3]);
        }
    }
}

// ---------------- K4: weighted combine + transpose to [B,D,16,16] ----------------
__global__ __launch_bounds__(256) void k4_comb(
    const float* __restrict__ slot, const float* __restrict__ route_w,
    float* __restrict__ out)
{
    __shared__ float cl[16][257];
    int bx = blockIdx.x;              // 0..511
    int b = bx >> 4; int hp = bx & 15;
    int tid = threadIdx.x;
    int d = tid;
    for (int wp = 0; wp < 16; wp++) {
        int n = (b * 16 + hp) * 16 + wp;
        float w0 = route_w[n * 2], w1 = route_w[n * 2 + 1];
        float v = w0 * slot[(size_t)(n * 2) * 256 + d] + w1 * slot[(size_t)(n * 2 + 1) * 256 + d];
        cl[wp][d] = v;
    }
    __syncthreads();
    int wp = tid & 15; int dg = tid >> 4;
    for (int r = 0; r < 16; r++) {
        int dd = r * 16 + dg;
        out[(((size_t)b * 256 + dd) * 16 + hp) * 16 + wp] = cl[wp][dd];
    }
    if (bx == 0 && tid == 0) out[(size_t)BN * 256] = 0.0f;
}

extern "C" void kernel_launch(void* const* d_in, const int* in_sizes, int n_in,
                              void* d_out, int out_size, void* d_ws, size_t ws_size,
                              hipStream_t stream)
{
    const float* x    = (const float*)d_in[0];
    const float* gw1  = (const float*)d_in[1];
    const float* gb1  = (const float*)d_in[2];
    const float* gw2  = (const float*)d_in[3];
    const float* gb2  = (const float*)d_in[4];
    const float* dw1w = (const float*)d_in[5];
    const float* dw1b = (const float*)d_in[6];
    const float* pw1w = (const float*)d_in[7];
    const float* pw1b = (const float*)d_in[8];
    const float* dw2w = (const float*)d_in[9];
    const float* dw2b = (const float*)d_in[10];
    const float* pw2w = (const float*)d_in[11];
    const float* pw2b = (const float*)d_in[12];
    const float* dw3w = (const float*)d_in[13];
    const float* dw3b = (const float*)d_in[14];
    const float* pw3w = (const float*)d_in[15];
    const float* pw3b = (const float*)d_in[16];

    char* ws = (char*)d_ws;
    int*   route_i = (int*)(ws + O_ROUTE_I);
    float* route_w = (float*)(ws + O_ROUTE_W);
    int*   counts  = (int*)(ws + O_COUNTS);
    int*   lists   = (int*)(ws + O_LISTS);
    float* pw2t    = (float*)(ws + O_PW2T);
    float* pw3t    = (float*)(ws + O_PW3T);
    float* slot    = (float*)(ws + O_SLOT);
    float* out     = (float*)d_out;

    hipLaunchKernelGGL(k0_prep, dim3(256), dim3(256), 0, stream,
                       pw2w, pw3w, pw2t, pw3t, counts);
    hipLaunchKernelGGL(k1_gate, dim3(BN / 16), dim3(256), 0, stream,
                       x, gw1, gb1, gw2, gb2, route_i, route_w, counts, lists);
    hipLaunchKernelGGL(k23_expert, dim3(8 * 2048), dim3(256), 0, stream,
                       x, counts, lists, dw1w, dw1b, pw1w, pw1b, dw2w, dw2b,
                       pw2t, pw2b, dw3w, dw3b, pw3t, pw3b, slot);
    hipLaunchKernelGGL(k4_comb, dim3(512), dim3(256), 0, stream,
                       slot, route_w, out);
}